// Round 1
// baseline (1256.563 us; speedup 1.0000x reference)
//
#include <hip/hip_runtime.h>
#include <hip/hip_bf16.h>
#include <cstdint>
#include <cstddef>

#define B_TOK 8192
#define DIM   1024
#define HID   4096
#define NEXP  8
#define MAXSLOT 17408  // B_TOK*2 (=16384) + NEXP*127 padding, rounded up

typedef __bf16 bf16x8 __attribute__((ext_vector_type(8)));
typedef float  f32x4  __attribute__((ext_vector_type(4)));

__device__ __forceinline__ void load_lds16(const void* g, void* l) {
  __builtin_amdgcn_global_load_lds(
      (const __attribute__((address_space(1))) void*)g,
      (__attribute__((address_space(3))) void*)l, 16, 0, 0);
}

// fp32 -> bf16 RNE (no NaN handling needed for this data)
__device__ __forceinline__ uint16_t f2b(float f) {
  uint32_t u = __builtin_bit_cast(uint32_t, f);
  uint32_t r = (u + 0x7FFFu + ((u >> 16) & 1u)) >> 16;
  return (uint16_t)r;
}

// ---------------- init / zero ----------------
__global__ void zero_out_kernel(float4* __restrict__ out) {
  out[(size_t)blockIdx.x * 256 + threadIdx.x] = make_float4(0.f, 0.f, 0.f, 0.f);
}

__global__ void init_kernel(int* __restrict__ rows16k, int* __restrict__ counts,
                            int* __restrict__ cursor, float* __restrict__ zeropad) {
  int i = blockIdx.x * 256 + threadIdx.x;
  if (i < MAXSLOT) rows16k[i] = -1;
  if (i < NEXP) { counts[i] = 0; cursor[i] = 0; }
  if (i < 16) zeropad[i] = 0.f;
}

// ---------------- conversions ----------------
__global__ void convert_x_kernel(const float* __restrict__ x, uint16_t* __restrict__ xb) {
  size_t i = ((size_t)blockIdx.x * 256 + threadIdx.x) * 4;
  float4 v = *(const float4*)(x + i);
  uint64_t p = (uint64_t)f2b(v.x) | ((uint64_t)f2b(v.y) << 16) |
               ((uint64_t)f2b(v.z) << 32) | ((uint64_t)f2b(v.w) << 48);
  *(uint64_t*)(xb + i) = p;
}

// out[n][m] = bf16(in[m][n]); per-expert slab of M*N elements. grid(N/32, M/32, E), block(32,8)
__global__ void transpose_cvt_kernel(const float* __restrict__ in, uint16_t* __restrict__ out,
                                     int M, int N) {
  __shared__ float tile[32][33];
  const size_t base = (size_t)blockIdx.z * M * N;
  const int x0 = blockIdx.x * 32, y0 = blockIdx.y * 32;
  const int tx = threadIdx.x, ty = threadIdx.y;
#pragma unroll
  for (int i = 0; i < 4; i++)
    tile[ty + i * 8][tx] = in[base + (size_t)(y0 + ty + i * 8) * N + x0 + tx];
  __syncthreads();
#pragma unroll
  for (int i = 0; i < 4; i++)
    out[base + (size_t)(x0 + ty + i * 8) * M + y0 + tx] = f2b(tile[tx][ty + i * 8]);
}

// ---------------- router ----------------
__global__ void router_kernel(const float* __restrict__ x, const float* __restrict__ Wr,
                              const float* __restrict__ br, int* __restrict__ top_i,
                              float* __restrict__ top_w, int* __restrict__ counts) {
  const int wave = threadIdx.x >> 6, lane = threadIdx.x & 63;
  const int b = blockIdx.x * 4 + wave;
  float acc[NEXP];
#pragma unroll
  for (int e = 0; e < NEXP; e++) acc[e] = 0.f;
  const float* xr = x + (size_t)b * DIM;
  for (int d = lane; d < DIM; d += 64) {
    float xv = xr[d];
    const float4* wr = (const float4*)(Wr + (size_t)d * NEXP);
    float4 w0 = wr[0], w1 = wr[1];
    acc[0] += xv * w0.x; acc[1] += xv * w0.y; acc[2] += xv * w0.z; acc[3] += xv * w0.w;
    acc[4] += xv * w1.x; acc[5] += xv * w1.y; acc[6] += xv * w1.z; acc[7] += xv * w1.w;
  }
#pragma unroll
  for (int e = 0; e < NEXP; e++)
#pragma unroll
    for (int off = 32; off; off >>= 1) acc[e] += __shfl_xor(acc[e], off);
  if (lane == 0) {
    float l[NEXP];
#pragma unroll
    for (int e = 0; e < NEXP; e++) l[e] = acc[e] + br[e];
    int i0 = 0; float v0 = l[0];
#pragma unroll
    for (int e = 1; e < NEXP; e++) if (l[e] > v0) { v0 = l[e]; i0 = e; }
    int i1 = -1; float v1 = -3.4e38f;
#pragma unroll
    for (int e = 0; e < NEXP; e++) if (e != i0 && l[e] > v1) { v1 = l[e]; i1 = e; }
    float w0 = 1.f / (1.f + expf(v1 - v0));
    float w1 = 1.f - w0;
    top_i[b * 2 + 0] = i0; top_i[b * 2 + 1] = i1;
    top_w[b * 2 + 0] = w0; top_w[b * 2 + 1] = w1;
    atomicAdd(&counts[i0], 1);
    atomicAdd(&counts[i1], 1);
  }
}

__global__ void offsets_kernel(const int* __restrict__ counts, int* __restrict__ off_p) {
  int o = 0;
  for (int e = 0; e < NEXP; e++) { off_p[e] = o; o += (counts[e] + 127) & ~127; }
  off_p[NEXP] = o;
}

__global__ void scatter_kernel(const int* __restrict__ top_i, const float* __restrict__ top_w,
                               const int* __restrict__ off_p, int* __restrict__ cursor,
                               int* __restrict__ rows16k, float* __restrict__ wgt) {
  int b = blockIdx.x * 256 + threadIdx.x;
  if (b >= B_TOK) return;
#pragma unroll
  for (int k = 0; k < 2; k++) {
    int e = top_i[b * 2 + k];
    int pos = off_p[e] + atomicAdd(&cursor[e], 1);
    rows16k[pos] = b;
    wgt[pos] = top_w[b * 2 + k];
  }
}

// ---------------- GEMM1: h = gelu(gather(x) @ W1[e] + b1[e]) ----------------
// grid(64, HID/128, NEXP), block 256. A gathered from xb via rows16k; B from W1b [e][h][d].
__global__ __launch_bounds__(256) void gemm1_kernel(
    const uint16_t* __restrict__ xb, const uint16_t* __restrict__ W1b,
    const float* __restrict__ b1, const int* __restrict__ rows16k,
    const int* __restrict__ counts, const int* __restrict__ off_p,
    const float* __restrict__ zeropad, uint16_t* __restrict__ h) {
  const int e = blockIdx.z;
  const int ne = counts[e];
  const int rb = blockIdx.x;
  if (rb * 128 >= ne) return;
  const int hbase = blockIdx.y * 128;
  const int sbase = off_p[e] + rb * 128;

  __shared__ __align__(16) uint16_t smemA[128 * 32];
  __shared__ __align__(16) uint16_t smemB[128 * 32];

  const int tid = threadIdx.x;
  const int lane = tid & 63;
  const int wm = (tid >> 7), wn = (tid >> 6) & 1;
  const int lr = lane & 15, lh = lane >> 4;

  const int r0 = tid >> 2, r1 = r0 + 64;
  const int c8 = (tid & 3) * 8;

  const int tokA0 = rows16k[sbase + r0];
  const int tokA1 = rows16k[sbase + r1];
  const uint16_t* zp = (const uint16_t*)zeropad;
  const uint16_t* srcA0 = (tokA0 >= 0) ? (xb + (size_t)tokA0 * DIM + c8) : zp;
  const uint16_t* srcA1 = (tokA1 >= 0) ? (xb + (size_t)tokA1 * DIM + c8) : zp;
  const int stA0 = (tokA0 >= 0) ? 32 : 0;
  const int stA1 = (tokA1 >= 0) ? 32 : 0;
  const uint16_t* srcB0 = W1b + ((size_t)e * HID + hbase + r0) * DIM + c8;
  const uint16_t* srcB1 = W1b + ((size_t)e * HID + hbase + r1) * DIM + c8;

  f32x4 acc[4][4];
#pragma unroll
  for (int mi = 0; mi < 4; mi++)
#pragma unroll
    for (int ni = 0; ni < 4; ni++) acc[mi][ni] = (f32x4){0.f, 0.f, 0.f, 0.f};

  for (int kt = 0; kt < DIM / 32; ++kt) {
    load_lds16(srcA0, &smemA[tid * 8]);
    load_lds16(srcA1, &smemA[(tid + 256) * 8]);
    load_lds16(srcB0, &smemB[tid * 8]);
    load_lds16(srcB1, &smemB[(tid + 256) * 8]);
    srcA0 += stA0; srcA1 += stA1; srcB0 += 32; srcB1 += 32;
    __syncthreads();
    bf16x8 a[4], bb[4];
#pragma unroll
    for (int mi = 0; mi < 4; mi++)
      a[mi] = *(const bf16x8*)&smemA[(wm * 64 + mi * 16 + lr) * 32 + lh * 8];
#pragma unroll
    for (int ni = 0; ni < 4; ni++)
      bb[ni] = *(const bf16x8*)&smemB[(wn * 64 + ni * 16 + lr) * 32 + lh * 8];
#pragma unroll
    for (int mi = 0; mi < 4; mi++)
#pragma unroll
      for (int ni = 0; ni < 4; ni++)
        acc[mi][ni] = __builtin_amdgcn_mfma_f32_16x16x32_bf16(a[mi], bb[ni], acc[mi][ni], 0, 0, 0);
    __syncthreads();
  }

#pragma unroll
  for (int mi = 0; mi < 4; mi++)
#pragma unroll
    for (int ni = 0; ni < 4; ni++)
#pragma unroll
      for (int r = 0; r < 4; r++) {
        int row = wm * 64 + mi * 16 + lh * 4 + r;
        int col = hbase + wn * 64 + ni * 16 + lr;
        float t = acc[mi][ni][r] + b1[e * HID + col];
        float g = 0.5f * t * (1.f + erff(t * 0.70710678118654752f));
        h[(size_t)(sbase + row) * HID + col] = f2b(g);
      }
}

// ---------------- GEMM2: out[tok] += w * (h @ W2[e] + b2[e]) ----------------
// grid(64, DIM/128, NEXP), block 256.
__global__ __launch_bounds__(256) void gemm2_kernel(
    const uint16_t* __restrict__ h, const uint16_t* __restrict__ W2b,
    const float* __restrict__ b2, const int* __restrict__ rows16k,
    const float* __restrict__ wgt, const int* __restrict__ counts,
    const int* __restrict__ off_p, float* __restrict__ out) {
  const int e = blockIdx.z;
  const int ne = counts[e];
  const int rb = blockIdx.x;
  if (rb * 128 >= ne) return;
  const int dbase = blockIdx.y * 128;
  const int sbase = off_p[e] + rb * 128;

  __shared__ __align__(16) uint16_t smemA[128 * 32];
  __shared__ __align__(16) uint16_t smemB[128 * 32];

  const int tid = threadIdx.x;
  const int lane = tid & 63;
  const int wm = (tid >> 7), wn = (tid >> 6) & 1;
  const int lr = lane & 15, lh = lane >> 4;

  const int r0 = tid >> 2, r1 = r0 + 64;
  const int c8 = (tid & 3) * 8;

  const uint16_t* srcA0 = h + (size_t)(sbase + r0) * HID + c8;
  const uint16_t* srcA1 = h + (size_t)(sbase + r1) * HID + c8;
  const uint16_t* srcB0 = W2b + ((size_t)e * DIM + dbase + r0) * HID + c8;
  const uint16_t* srcB1 = W2b + ((size_t)e * DIM + dbase + r1) * HID + c8;

  f32x4 acc[4][4];
#pragma unroll
  for (int mi = 0; mi < 4; mi++)
#pragma unroll
    for (int ni = 0; ni < 4; ni++) acc[mi][ni] = (f32x4){0.f, 0.f, 0.f, 0.f};

  for (int kt = 0; kt < HID / 32; ++kt) {
    load_lds16(srcA0, &smemA[tid * 8]);
    load_lds16(srcA1, &smemA[(tid + 256) * 8]);
    load_lds16(srcB0, &smemB[tid * 8]);
    load_lds16(srcB1, &smemB[(tid + 256) * 8]);
    srcA0 += 32; srcA1 += 32; srcB0 += 32; srcB1 += 32;
    __syncthreads();
    bf16x8 a[4], bb[4];
#pragma unroll
    for (int mi = 0; mi < 4; mi++)
      a[mi] = *(const bf16x8*)&smemA[(wm * 64 + mi * 16 + lr) * 32 + lh * 8];
#pragma unroll
    for (int ni = 0; ni < 4; ni++)
      bb[ni] = *(const bf16x8*)&smemB[(wn * 64 + ni * 16 + lr) * 32 + lh * 8];
#pragma unroll
    for (int mi = 0; mi < 4; mi++)
#pragma unroll
      for (int ni = 0; ni < 4; ni++)
        acc[mi][ni] = __builtin_amdgcn_mfma_f32_16x16x32_bf16(a[mi], bb[ni], acc[mi][ni], 0, 0, 0);
    __syncthreads();
  }

  int tok[4][4]; float wv[4][4];
#pragma unroll
  for (int mi = 0; mi < 4; mi++)
#pragma unroll
    for (int r = 0; r < 4; r++) {
      int row = wm * 64 + mi * 16 + lh * 4 + r;
      tok[mi][r] = rows16k[sbase + row];
      wv[mi][r] = wgt[sbase + row];
    }
#pragma unroll
  for (int mi = 0; mi < 4; mi++)
#pragma unroll
    for (int ni = 0; ni < 4; ni++)
#pragma unroll
      for (int r = 0; r < 4; r++) {
        if (tok[mi][r] >= 0) {
          int col = dbase + wn * 64 + ni * 16 + lr;
          float t = acc[mi][ni][r] + b2[e * DIM + col];
          atomicAdd(out + (size_t)tok[mi][r] * DIM + col, wv[mi][r] * t);
        }
      }
}

// ---------------- launch ----------------
extern "C" void kernel_launch(void* const* d_in, const int* in_sizes, int n_in,
                              void* d_out, int out_size, void* d_ws, size_t ws_size,
                              hipStream_t stream) {
  const float* x  = (const float*)d_in[0];
  const float* Wr = (const float*)d_in[1];
  const float* br = (const float*)d_in[2];
  const float* W1 = (const float*)d_in[3];
  const float* b1 = (const float*)d_in[4];
  const float* W2 = (const float*)d_in[5];
  const float* b2 = (const float*)d_in[6];
  float* out = (float*)d_out;

  char* ws = (char*)d_ws;
  uint16_t* W1b = (uint16_t*)ws; ws += (size_t)NEXP * HID * DIM * 2;   // 64 MB
  uint16_t* W2b = (uint16_t*)ws; ws += (size_t)NEXP * DIM * HID * 2;   // 64 MB
  uint16_t* xb  = (uint16_t*)ws; ws += (size_t)B_TOK * DIM * 2;        // 16 MB
  uint16_t* h   = (uint16_t*)ws; ws += (size_t)MAXSLOT * HID * 2;      // 136 MB
  int*   top_i  = (int*)ws;   ws += (size_t)B_TOK * 2 * 4;
  float* top_w  = (float*)ws; ws += (size_t)B_TOK * 2 * 4;
  int*   rows16k= (int*)ws;   ws += (size_t)MAXSLOT * 4;
  float* wgt    = (float*)ws; ws += (size_t)MAXSLOT * 4;
  int*   counts = (int*)ws;   ws += 64;
  int*   cursor = (int*)ws;   ws += 64;
  int*   off_p  = (int*)ws;   ws += 64;
  float* zeropad= (float*)ws; ws += 64;

  zero_out_kernel<<<dim3((B_TOK * DIM / 4) / 256), dim3(256), 0, stream>>>((float4*)out);
  init_kernel<<<dim3((MAXSLOT + 255) / 256), dim3(256), 0, stream>>>(rows16k, counts, cursor, zeropad);
  convert_x_kernel<<<dim3((B_TOK * DIM / 4) / 256), dim3(256), 0, stream>>>(x, xb);
  transpose_cvt_kernel<<<dim3(HID / 32, DIM / 32, NEXP), dim3(32, 8), 0, stream>>>(W1, W1b, DIM, HID);
  transpose_cvt_kernel<<<dim3(DIM / 32, HID / 32, NEXP), dim3(32, 8), 0, stream>>>(W2, W2b, HID, DIM);
  router_kernel<<<dim3(B_TOK / 4), dim3(256), 0, stream>>>(x, Wr, br, top_i, top_w, counts);
  offsets_kernel<<<dim3(1), dim3(1), 0, stream>>>(counts, off_p);
  scatter_kernel<<<dim3(B_TOK / 256), dim3(256), 0, stream>>>(top_i, top_w, off_p, cursor, rows16k, wgt);
  gemm1_kernel<<<dim3(64, HID / 128, NEXP), dim3(256), 0, stream>>>(xb, W1b, b1, rows16k, counts, off_p, zeropad, h);
  gemm2_kernel<<<dim3(64, DIM / 128, NEXP), dim3(256), 0, stream>>>(h, W2b, b2, rows16k, wgt, counts, off_p, out);
}

// Round 2
// 1183.883 us; speedup vs baseline: 1.0614x; 1.0614x over previous
//
#include <hip/hip_runtime.h>
#include <hip/hip_bf16.h>
#include <cstdint>
#include <cstddef>

#define B_TOK 8192
#define DIM   1024
#define HID   4096
#define NEXP  8
#define MAXSLOT 17408  // B_TOK*2 (=16384) + NEXP*127 padding, rounded up

typedef __bf16 bf16x8 __attribute__((ext_vector_type(8)));
typedef float  f32x4  __attribute__((ext_vector_type(4)));

__device__ __forceinline__ void load_lds16(const void* g, void* l) {
  __builtin_amdgcn_global_load_lds(
      (const __attribute__((address_space(1))) void*)g,
      (__attribute__((address_space(3))) void*)l, 16, 0, 0);
}

// fp32 -> bf16 RNE
__device__ __forceinline__ uint16_t f2b(float f) {
  uint32_t u = __builtin_bit_cast(uint32_t, f);
  return (uint16_t)((u + 0x7FFFu + ((u >> 16) & 1u)) >> 16);
}
__device__ __forceinline__ float b2f(uint32_t hbits) {
  uint32_t u = hbits << 16;
  return __builtin_bit_cast(float, u);
}

// ---------------- init ----------------
__global__ void init_kernel(int* __restrict__ rows16k, int* __restrict__ counts,
                            int* __restrict__ cursor, float* __restrict__ zeropad) {
  int i = blockIdx.x * 256 + threadIdx.x;
  if (i < MAXSLOT) rows16k[i] = -1;
  if (i < NEXP) { counts[i] = 0; cursor[i] = 0; }
  if (i < 16) zeropad[i] = 0.f;
}

// ---------------- conversions ----------------
__global__ void convert_x_kernel(const float* __restrict__ x, uint16_t* __restrict__ xb) {
  size_t i = ((size_t)blockIdx.x * 256 + threadIdx.x) * 4;
  float4 v = *(const float4*)(x + i);
  uint64_t p = (uint64_t)f2b(v.x) | ((uint64_t)f2b(v.y) << 16) |
               ((uint64_t)f2b(v.z) << 32) | ((uint64_t)f2b(v.w) << 48);
  *(uint64_t*)(xb + i) = p;
}

// out[n][m] = bf16(in[m][n]); per-expert slab. grid(N/32, M/32, E), block(32,8)
__global__ void transpose_cvt_kernel(const float* __restrict__ in, uint16_t* __restrict__ out,
                                     int M, int N) {
  __shared__ float tile[32][33];
  const size_t base = (size_t)blockIdx.z * M * N;
  const int x0 = blockIdx.x * 32, y0 = blockIdx.y * 32;
  const int tx = threadIdx.x, ty = threadIdx.y;
#pragma unroll
  for (int i = 0; i < 4; i++)
    tile[ty + i * 8][tx] = in[base + (size_t)(y0 + ty + i * 8) * N + x0 + tx];
  __syncthreads();
#pragma unroll
  for (int i = 0; i < 4; i++)
    out[base + (size_t)(x0 + ty + i * 8) * M + y0 + tx] = f2b(tile[tx][ty + i * 8]);
}

// ---------------- router ----------------
__global__ void router_kernel(const float* __restrict__ x, const float* __restrict__ Wr,
                              const float* __restrict__ br, int* __restrict__ top_i,
                              float* __restrict__ top_w, int* __restrict__ counts) {
  const int wave = threadIdx.x >> 6, lane = threadIdx.x & 63;
  const int b = blockIdx.x * 4 + wave;
  float acc[NEXP];
#pragma unroll
  for (int e = 0; e < NEXP; e++) acc[e] = 0.f;
  const float* xr = x + (size_t)b * DIM;
  for (int d = lane; d < DIM; d += 64) {
    float xv = xr[d];
    const float4* wr = (const float4*)(Wr + (size_t)d * NEXP);
    float4 w0 = wr[0], w1 = wr[1];
    acc[0] += xv * w0.x; acc[1] += xv * w0.y; acc[2] += xv * w0.z; acc[3] += xv * w0.w;
    acc[4] += xv * w1.x; acc[5] += xv * w1.y; acc[6] += xv * w1.z; acc[7] += xv * w1.w;
  }
#pragma unroll
  for (int e = 0; e < NEXP; e++)
#pragma unroll
    for (int off = 32; off; off >>= 1) acc[e] += __shfl_xor(acc[e], off);
  if (lane == 0) {
    float l[NEXP];
#pragma unroll
    for (int e = 0; e < NEXP; e++) l[e] = acc[e] + br[e];
    int i0 = 0; float v0 = l[0];
#pragma unroll
    for (int e = 1; e < NEXP; e++) if (l[e] > v0) { v0 = l[e]; i0 = e; }
    int i1 = -1; float v1 = -3.4e38f;
#pragma unroll
    for (int e = 0; e < NEXP; e++) if (e != i0 && l[e] > v1) { v1 = l[e]; i1 = e; }
    float w0 = 1.f / (1.f + expf(v1 - v0));
    float w1 = 1.f - w0;
    top_i[b * 2 + 0] = i0; top_i[b * 2 + 1] = i1;
    top_w[b * 2 + 0] = w0; top_w[b * 2 + 1] = w1;
    atomicAdd(&counts[i0], 1);
    atomicAdd(&counts[i1], 1);
  }
}

__global__ void offsets_kernel(const int* __restrict__ counts, int* __restrict__ off_p) {
  int o = 0;
  for (int e = 0; e < NEXP; e++) { off_p[e] = o; o += (counts[e] + 127) & ~127; }
  off_p[NEXP] = o;
}

__global__ void scatter_kernel(const int* __restrict__ top_i, const float* __restrict__ top_w,
                               const int* __restrict__ off_p, int* __restrict__ cursor,
                               int* __restrict__ rows16k, float* __restrict__ wgt,
                               int* __restrict__ slot_of) {
  int b = blockIdx.x * 256 + threadIdx.x;
  if (b >= B_TOK) return;
#pragma unroll
  for (int k = 0; k < 2; k++) {
    int e = top_i[b * 2 + k];
    int pos = off_p[e] + atomicAdd(&cursor[e], 1);
    rows16k[pos] = b;
    wgt[pos] = top_w[b * 2 + k];
    slot_of[b * 2 + k] = pos;
  }
}

// ---------------- GEMM1: h = gelu(gather(x) @ W1[e]^T_layout + b1[e]) ----------------
// Tiles 128x128, BK=64, XOR chunk swizzle (chunk ^= row&7) on both stage-source and read.
// grid(64, HID/128, NEXP), block 256.
__global__ __launch_bounds__(256) void gemm1_kernel(
    const uint16_t* __restrict__ xb, const uint16_t* __restrict__ W1b,
    const float* __restrict__ b1, const int* __restrict__ rows16k,
    const int* __restrict__ counts, const int* __restrict__ off_p,
    const float* __restrict__ zeropad, uint16_t* __restrict__ h) {
  const int e = blockIdx.z;
  const int ne = counts[e];
  const int rb = blockIdx.x;
  if (rb * 128 >= ne) return;
  const int hbase = blockIdx.y * 128;
  const int sbase = off_p[e] + rb * 128;

  __shared__ __align__(16) uint16_t smemA[128 * 64];
  __shared__ __align__(16) uint16_t smemB[128 * 64];

  const int tid = threadIdx.x;
  const int lane = tid & 63;
  const int wm = tid >> 7, wn = (tid >> 6) & 1;
  const int lr = lane & 15, lh = lane >> 4;
  const int swz8 = (((tid & 7) ^ ((tid >> 3) & 7)) * 8);  // pre-swizzled source chunk

  const uint16_t* zp = (const uint16_t*)zeropad;
  const uint16_t* srcA[4]; int stA[4];
  const uint16_t* srcB[4];
#pragma unroll
  for (int is = 0; is < 4; is++) {
    int r = (tid >> 3) + is * 32;
    int tok = rows16k[sbase + r];
    srcA[is] = (tok >= 0) ? (xb + (size_t)tok * DIM + swz8) : zp;
    stA[is] = (tok >= 0) ? 64 : 0;
    srcB[is] = W1b + ((size_t)e * HID + hbase + r) * DIM + swz8;
  }

  f32x4 acc[4][4];
#pragma unroll
  for (int mi = 0; mi < 4; mi++)
#pragma unroll
    for (int ni = 0; ni < 4; ni++) acc[mi][ni] = (f32x4){0.f, 0.f, 0.f, 0.f};

  for (int kt = 0; kt < DIM / 64; ++kt) {
#pragma unroll
    for (int is = 0; is < 4; is++) {
      load_lds16(srcA[is], &smemA[(is * 256 + tid) * 8]);
      load_lds16(srcB[is], &smemB[(is * 256 + tid) * 8]);
      srcA[is] += stA[is]; srcB[is] += 64;
    }
    __syncthreads();
#pragma unroll
    for (int kk = 0; kk < 2; kk++) {
      bf16x8 a[4], bb[4];
      const int rc = (kk * 4 + lh) ^ (lr & 7);  // swizzled read chunk (row&7 == lr&7)
#pragma unroll
      for (int mi = 0; mi < 4; mi++)
        a[mi] = *(const bf16x8*)&smemA[(wm * 64 + mi * 16 + lr) * 64 + rc * 8];
#pragma unroll
      for (int ni = 0; ni < 4; ni++)
        bb[ni] = *(const bf16x8*)&smemB[(wn * 64 + ni * 16 + lr) * 64 + rc * 8];
#pragma unroll
      for (int mi = 0; mi < 4; mi++)
#pragma unroll
        for (int ni = 0; ni < 4; ni++)
          acc[mi][ni] = __builtin_amdgcn_mfma_f32_16x16x32_bf16(a[mi], bb[ni], acc[mi][ni], 0, 0, 0);
    }
    __syncthreads();
  }

  float bias[4];
#pragma unroll
  for (int ni = 0; ni < 4; ni++) bias[ni] = b1[e * HID + hbase + wn * 64 + ni * 16 + lr];
#pragma unroll
  for (int mi = 0; mi < 4; mi++)
#pragma unroll
    for (int ni = 0; ni < 4; ni++)
#pragma unroll
      for (int r = 0; r < 4; r++) {
        int row = wm * 64 + mi * 16 + lh * 4 + r;
        int col = hbase + wn * 64 + ni * 16 + lr;
        float t = acc[mi][ni][r] + bias[ni];
        float g = 0.5f * t * (1.f + erff(t * 0.70710678118654752f));
        h[(size_t)(sbase + row) * HID + col] = f2b(g);
      }
}

// ---------------- GEMM2: y[slot] = h @ W2[e]^T_layout + b2[e] (bf16 store, no atomics) ----------------
// grid(64, DIM/128, NEXP), block 256.
__global__ __launch_bounds__(256) void gemm2_kernel(
    const uint16_t* __restrict__ h, const uint16_t* __restrict__ W2b,
    const float* __restrict__ b2, const int* __restrict__ counts,
    const int* __restrict__ off_p, uint16_t* __restrict__ y) {
  const int e = blockIdx.z;
  const int ne = counts[e];
  const int rb = blockIdx.x;
  if (rb * 128 >= ne) return;
  const int dbase = blockIdx.y * 128;
  const int sbase = off_p[e] + rb * 128;

  __shared__ __align__(16) uint16_t smemA[128 * 64];
  __shared__ __align__(16) uint16_t smemB[128 * 64];

  const int tid = threadIdx.x;
  const int lane = tid & 63;
  const int wm = tid >> 7, wn = (tid >> 6) & 1;
  const int lr = lane & 15, lh = lane >> 4;
  const int swz8 = (((tid & 7) ^ ((tid >> 3) & 7)) * 8);

  const uint16_t* srcA[4];
  const uint16_t* srcB[4];
#pragma unroll
  for (int is = 0; is < 4; is++) {
    int r = (tid >> 3) + is * 32;
    srcA[is] = h + (size_t)(sbase + r) * HID + swz8;
    srcB[is] = W2b + ((size_t)e * DIM + dbase + r) * HID + swz8;
  }

  f32x4 acc[4][4];
#pragma unroll
  for (int mi = 0; mi < 4; mi++)
#pragma unroll
    for (int ni = 0; ni < 4; ni++) acc[mi][ni] = (f32x4){0.f, 0.f, 0.f, 0.f};

  for (int kt = 0; kt < HID / 64; ++kt) {
#pragma unroll
    for (int is = 0; is < 4; is++) {
      load_lds16(srcA[is], &smemA[(is * 256 + tid) * 8]);
      load_lds16(srcB[is], &smemB[(is * 256 + tid) * 8]);
      srcA[is] += 64; srcB[is] += 64;
    }
    __syncthreads();
#pragma unroll
    for (int kk = 0; kk < 2; kk++) {
      bf16x8 a[4], bb[4];
      const int rc = (kk * 4 + lh) ^ (lr & 7);
#pragma unroll
      for (int mi = 0; mi < 4; mi++)
        a[mi] = *(const bf16x8*)&smemA[(wm * 64 + mi * 16 + lr) * 64 + rc * 8];
#pragma unroll
      for (int ni = 0; ni < 4; ni++)
        bb[ni] = *(const bf16x8*)&smemB[(wn * 64 + ni * 16 + lr) * 64 + rc * 8];
#pragma unroll
      for (int mi = 0; mi < 4; mi++)
#pragma unroll
        for (int ni = 0; ni < 4; ni++)
          acc[mi][ni] = __builtin_amdgcn_mfma_f32_16x16x32_bf16(a[mi], bb[ni], acc[mi][ni], 0, 0, 0);
    }
    __syncthreads();
  }

  float bias[4];
#pragma unroll
  for (int ni = 0; ni < 4; ni++) bias[ni] = b2[e * DIM + dbase + wn * 64 + ni * 16 + lr];
#pragma unroll
  for (int mi = 0; mi < 4; mi++)
#pragma unroll
    for (int ni = 0; ni < 4; ni++)
#pragma unroll
      for (int r = 0; r < 4; r++) {
        int row = wm * 64 + mi * 16 + lh * 4 + r;
        int col = dbase + wn * 64 + ni * 16 + lr;
        y[(size_t)(sbase + row) * DIM + col] = f2b(acc[mi][ni][r] + bias[ni]);
      }
}

// ---------------- combine: out[b] = w0*y[slot0] + w1*y[slot1] ----------------
// grid(B_TOK), block 256; thread t covers cols 4t..4t+3.
__global__ void combine_kernel(const uint16_t* __restrict__ y, const int* __restrict__ slot_of,
                               const float* __restrict__ top_w, float* __restrict__ out) {
  const int b = blockIdx.x;
  const int t = threadIdx.x;
  const int s0 = slot_of[b * 2], s1 = slot_of[b * 2 + 1];
  const float w0 = top_w[b * 2], w1 = top_w[b * 2 + 1];
  uint64_t p0 = *(const uint64_t*)(y + (size_t)s0 * DIM + t * 4);
  uint64_t p1 = *(const uint64_t*)(y + (size_t)s1 * DIM + t * 4);
  float4 r;
  r.x = w0 * b2f((uint32_t)(p0 >> 0) & 0xFFFFu)  + w1 * b2f((uint32_t)(p1 >> 0) & 0xFFFFu);
  r.y = w0 * b2f((uint32_t)(p0 >> 16) & 0xFFFFu) + w1 * b2f((uint32_t)(p1 >> 16) & 0xFFFFu);
  r.z = w0 * b2f((uint32_t)(p0 >> 32) & 0xFFFFu) + w1 * b2f((uint32_t)(p1 >> 32) & 0xFFFFu);
  r.w = w0 * b2f((uint32_t)(p0 >> 48) & 0xFFFFu) + w1 * b2f((uint32_t)(p1 >> 48) & 0xFFFFu);
  *(float4*)(out + (size_t)b * DIM + t * 4) = r;
}

// ---------------- launch ----------------
extern "C" void kernel_launch(void* const* d_in, const int* in_sizes, int n_in,
                              void* d_out, int out_size, void* d_ws, size_t ws_size,
                              hipStream_t stream) {
  const float* x  = (const float*)d_in[0];
  const float* Wr = (const float*)d_in[1];
  const float* br = (const float*)d_in[2];
  const float* W1 = (const float*)d_in[3];
  const float* b1 = (const float*)d_in[4];
  const float* W2 = (const float*)d_in[5];
  const float* b2 = (const float*)d_in[6];
  float* out = (float*)d_out;

  char* ws = (char*)d_ws;
  uint16_t* W1b = (uint16_t*)ws; ws += (size_t)NEXP * HID * DIM * 2;   // 64 MB
  uint16_t* W2b = (uint16_t*)ws; ws += (size_t)NEXP * DIM * HID * 2;   // 64 MB
  uint16_t* xb  = (uint16_t*)ws; ws += (size_t)B_TOK * DIM * 2;        // 16 MB
  uint16_t* h   = (uint16_t*)ws; ws += (size_t)MAXSLOT * HID * 2;      // 136 MB
  uint16_t* yb  = (uint16_t*)ws; ws += (size_t)MAXSLOT * DIM * 2;      // 34 MB
  int*   top_i  = (int*)ws;   ws += (size_t)B_TOK * 2 * 4;
  float* top_w  = (float*)ws; ws += (size_t)B_TOK * 2 * 4;
  int*   slot_of= (int*)ws;   ws += (size_t)B_TOK * 2 * 4;
  int*   rows16k= (int*)ws;   ws += (size_t)MAXSLOT * 4;
  float* wgt    = (float*)ws; ws += (size_t)MAXSLOT * 4;
  int*   counts = (int*)ws;   ws += 64;
  int*   cursor = (int*)ws;   ws += 64;
  int*   off_p  = (int*)ws;   ws += 64;
  float* zeropad= (float*)ws; ws += 64;

  init_kernel<<<dim3((MAXSLOT + 255) / 256), dim3(256), 0, stream>>>(rows16k, counts, cursor, zeropad);
  convert_x_kernel<<<dim3((B_TOK * DIM / 4) / 256), dim3(256), 0, stream>>>(x, xb);
  transpose_cvt_kernel<<<dim3(HID / 32, DIM / 32, NEXP), dim3(32, 8), 0, stream>>>(W1, W1b, DIM, HID);
  transpose_cvt_kernel<<<dim3(DIM / 32, HID / 32, NEXP), dim3(32, 8), 0, stream>>>(W2, W2b, HID, DIM);
  router_kernel<<<dim3(B_TOK / 4), dim3(256), 0, stream>>>(x, Wr, br, top_i, top_w, counts);
  offsets_kernel<<<dim3(1), dim3(1), 0, stream>>>(counts, off_p);
  scatter_kernel<<<dim3(B_TOK / 256), dim3(256), 0, stream>>>(top_i, top_w, off_p, cursor, rows16k, wgt, slot_of);
  gemm1_kernel<<<dim3(64, HID / 128, NEXP), dim3(256), 0, stream>>>(xb, W1b, b1, rows16k, counts, off_p, zeropad, h);
  gemm2_kernel<<<dim3(64, DIM / 128, NEXP), dim3(256), 0, stream>>>(h, W2b, b2, counts, off_p, yb);
  combine_kernel<<<dim3(B_TOK), dim3(256), 0, stream>>>(yb, slot_of, top_w, out);
}